// Round 4
// baseline (1010.928 us; speedup 1.0000x reference)
//
#include <hip/hip_runtime.h>
#include <hip/hip_bf16.h>

typedef __attribute__((ext_vector_type(8))) short short8;
typedef __attribute__((ext_vector_type(4))) float floatx4;

#define NSEQ 16
#define SEQ 128
#define DIM 256
#define HID 256
#define K3H 768
#define K2D 512
#define LOG2E 1.442695041f
#define LOG2E2 2.885390082f

__device__ __forceinline__ float frcp(float x) { return __builtin_amdgcn_rcpf(x); }
__device__ __forceinline__ float fsigmoid(float x) { return frcp(1.f + __expf(-x)); }
__device__ __forceinline__ float ftanh(float x) {
    return 1.f - 2.f * frcp(1.f + __expf(2.f * x));
}
__device__ __forceinline__ unsigned short bf16bits(float v) {
    unsigned u = __builtin_bit_cast(unsigned, v);
    unsigned r = (u + 0x7FFFu + ((u >> 16) & 1u)) >> 16;
    return (unsigned short)r;
}

// ---------------- K1: left = x@w1, right = x@w2  (8 rows/block, v2-proven) ----------------
__global__ __launch_bounds__(256) void k1_leftright(
        const float* __restrict__ x, const float* __restrict__ w1,
        const float* __restrict__ w2, float* __restrict__ left,
        float* __restrict__ right) {
    __shared__ __align__(16) float xs[8][DIM];
    const int tid = threadIdx.x;
    const int r0 = blockIdx.x * 8;
    #pragma unroll
    for (int i = 0; i < 8; ++i) xs[i][tid] = x[(r0 + i) * DIM + tid];
    __syncthreads();
    float accL[8], accR[8];
    #pragma unroll
    for (int i = 0; i < 8; ++i) { accL[i] = 0.f; accR[i] = 0.f; }
    #pragma unroll 4
    for (int d = 0; d < DIM; ++d) {
        float wa = w1[d * DIM + tid];
        float wb = w2[d * DIM + tid];
        #pragma unroll
        for (int i = 0; i < 8; ++i) {
            float xv = xs[i][d];
            accL[i] = fmaf(xv, wa, accL[i]);
            accR[i] = fmaf(xv, wb, accR[i]);
        }
    }
    #pragma unroll
    for (int i = 0; i < 8; ++i) {
        left[(r0 + i) * DIM + tid]  = accL[i];
        right[(r0 + i) * DIM + tid] = accR[i];
    }
}

// ---------------- K2: scores (tanh, v3 dot), softmax, c = score@x ----------------
__global__ __launch_bounds__(128) void k2_attn(
        const float* __restrict__ x, const float* __restrict__ left,
        const float* __restrict__ right, const float* __restrict__ bias,
        const float* __restrict__ v3, float* __restrict__ cout) {
    __shared__ __align__(16) float lm[DIM];
    __shared__ __align__(16) float v3s[DIM];
    __shared__ float p[SEQ];
    __shared__ float red[2];
    const int tid = threadIdx.x;      // 0..127 (= n)
    const int lane = tid & 63;
    const int wid = tid >> 6;         // 0..1
    const int bm = blockIdx.x;        // 0..2047
    const int b = bm >> 7;            // sequence index

    const float* lrow = left + bm * DIM;
    #pragma unroll
    for (int q = 0; q < 2; ++q) {
        int d = tid + q * 128;
        lm[d]  = lrow[d] + bias[d];
        v3s[d] = v3[d];
    }
    __syncthreads();

    const float4* rrow = reinterpret_cast<const float4*>(right + (b * SEQ + tid) * DIM);
    const float4* lm4  = reinterpret_cast<const float4*>(lm);
    const float4* vv4  = reinterpret_cast<const float4*>(v3s);
    float s = 0.f;
    for (int d4 = 0; d4 < DIM / 4; ++d4) {
        float4 rv = rrow[d4];
        float4 lv = lm4[d4];
        float4 vv = vv4[d4];
        s = fmaf(ftanh(lv.x + rv.x), vv.x, s);
        s = fmaf(ftanh(lv.y + rv.y), vv.y, s);
        s = fmaf(ftanh(lv.z + rv.z), vv.z, s);
        s = fmaf(ftanh(lv.w + rv.w), vv.w, s);
    }
    float m = s;
    #pragma unroll
    for (int off = 32; off >= 1; off >>= 1) m = fmaxf(m, __shfl_xor(m, off, 64));
    if (lane == 0) red[wid] = m;
    __syncthreads();
    m = fmaxf(red[0], red[1]);
    float e = __expf(s - m);
    float t = e;
    #pragma unroll
    for (int off = 32; off >= 1; off >>= 1) t += __shfl_xor(t, off, 64);
    __syncthreads();
    if (lane == 0) red[wid] = t;
    __syncthreads();
    float denom = red[0] + red[1];
    p[tid] = e * frcp(denom);
    __syncthreads();

    const float* xb = x + b * SEQ * DIM;
    float c0 = 0.f, c1 = 0.f;
    #pragma unroll 4
    for (int n = 0; n < SEQ; ++n) {
        float pn = p[n];
        c0 = fmaf(pn, xb[n * DIM + tid], c0);
        c1 = fmaf(pn, xb[n * DIM + tid + 128], c1);
    }
    cout[bm * DIM + tid]       = c0;
    cout[bm * DIM + tid + 128] = c1;
}

// ---------------- K3: xp = [x, c] @ gru_kernel + b_in  (8 rows/block) ----------------
// z/r outputs prescaled by log2e, h outputs by 2*log2e so k4's sigmoid/tanh
// become bare v_exp (exp2) with negate modifiers.
__global__ __launch_bounds__(256) void k3_xproj(
        const float* __restrict__ x, const float* __restrict__ c,
        const float* __restrict__ gk, const float* __restrict__ gbias,
        float* __restrict__ xp) {
    __shared__ __align__(16) float xc[8][K2D];
    const int tid = threadIdx.x;
    const int r0 = blockIdx.x * 8;
    #pragma unroll
    for (int i = 0; i < 8; ++i) {
        xc[i][tid]       = x[(r0 + i) * DIM + tid];
        xc[i][tid + 256] = c[(r0 + i) * DIM + tid];
    }
    __syncthreads();
    float acc[8][3];
    #pragma unroll
    for (int i = 0; i < 8; ++i) {
        acc[i][0] = gbias[tid];
        acc[i][1] = gbias[256 + tid];
        acc[i][2] = gbias[512 + tid];
    }
    #pragma unroll 2
    for (int k = 0; k < K2D; ++k) {
        float g0 = gk[k * K3H + tid];
        float g1 = gk[k * K3H + 256 + tid];
        float g2 = gk[k * K3H + 512 + tid];
        #pragma unroll
        for (int i = 0; i < 8; ++i) {
            float xv = xc[i][k];
            acc[i][0] = fmaf(xv, g0, acc[i][0]);
            acc[i][1] = fmaf(xv, g1, acc[i][1]);
            acc[i][2] = fmaf(xv, g2, acc[i][2]);
        }
    }
    #pragma unroll
    for (int i = 0; i < 8; ++i) {
        xp[(r0 + i) * K3H + tid]       = acc[i][0] * LOG2E;
        xp[(r0 + i) * K3H + 256 + tid] = acc[i][1] * LOG2E;
        xp[(r0 + i) * K3H + 512 + tid] = acc[i][2] * LOG2E2;
    }
}

// ---------------- K4: GRU recurrence v4 — ALL 16 sequences in ONE block ----------------
// 1024 threads = 16 waves. Wave wv owns output column d = wv*16 + (lane&15) of all
// three gates (cols u*256+d, u=0:z 1:r 2:h). MFMA A = h for all 16 seqs (M=16 fully
// used): total MFMA work drops 16x vs per-sequence blocks. C/D layout row=(lane>>4)*4
// +reg = seq, col=lane&15 -> each lane's C[u][j] are rz/rr/rh for its 4 (seq,d) pairs:
// gates fully in-register. Weights bf16 in 96 VGPRs/lane, prescaled by log2e (z,r) /
// 2log2e (h); bias pre-folded into C-init. One lgkm-only barrier per step; hbf double-
// buffered; A-frag ds_read_b128 is 16-lane-broadcast, conflict-free.
__global__ __launch_bounds__(1024) void k4_gru(
        const float* __restrict__ rec, const float* __restrict__ gbias,
        const float* __restrict__ xp, float* __restrict__ out) {
    __shared__ __align__(16) float ws[16 * K3H];              // 48KB staging
    __shared__ __align__(16) unsigned short hbf[2][16][HID];  // 16KB dbuf h (bf16)
    const int tid  = threadIdx.x;
    const int lane = tid & 63;
    const int wv   = tid >> 6;       // 0..15
    const int l15  = lane & 15;
    const int g4   = lane >> 4;      // 0..3
    const int d    = wv * 16 + l15;  // owned output column 0..255

    // ---- Preload rec_kernel as prescaled bf16 B-fragments: Bf[u][kc] ----
    short8 Bf[3][8];
    #pragma unroll
    for (int part = 0; part < 16; ++part) {
        #pragma unroll
        for (int q = 0; q < 3; ++q) {
            int fi = q * 1024 + tid;   // 3072 float4 = 16*768 floats
            reinterpret_cast<float4*>(ws)[fi] =
                reinterpret_cast<const float4*>(rec + part * 16 * K3H)[fi];
        }
        __syncthreads();
        const int kc = part >> 1, half = part & 1;
        #pragma unroll
        for (int u = 0; u < 3; ++u) {
            const float sc = (u == 2) ? LOG2E2 : LOG2E;
            const int col = u * 256 + d;
            #pragma unroll
            for (int j = 0; j < 8; ++j) {
                int r = g4 * 8 + j;            // k within 32-chunk
                if ((r >> 4) == half)
                    Bf[u][kc][j] = (short)bf16bits(ws[(r & 15) * K3H + col] * sc);
            }
        }
        __syncthreads();
    }

    float br[3];
    br[0] = gbias[K3H + d] * LOG2E;
    br[1] = gbias[K3H + 256 + d] * LOG2E;
    br[2] = gbias[K3H + 512 + d] * LOG2E2;

    float h[4] = {0.f, 0.f, 0.f, 0.f};
    for (int i = tid; i < 16 * HID; i += 1024)
        reinterpret_cast<unsigned short*>(hbf[0])[i] = 0;

    for (int s = 0; s < SEQ; ++s) {
        const int cb = s & 1, nb = cb ^ 1;
        // raw barrier: LDS drained per-wave; global loads/stores stay in flight
        asm volatile("s_waitcnt lgkmcnt(0)\n\ts_barrier" ::: "memory");

        // gate inputs (prescaled in k3); issued early, consumed after MFMAs
        float xq[3][4];
        #pragma unroll
        for (int j = 0; j < 4; ++j) {
            const float* p = xp + (size_t)((g4 * 4 + j) * SEQ + s) * K3H + d;
            xq[0][j] = p[0];
            xq[1][j] = p[256];
            xq[2][j] = p[512];
        }

        // A-fragments: h rows for all 16 seqs (row = l&15), 16-lane broadcast reads
        short8 av[8];
        #pragma unroll
        for (int kc = 0; kc < 8; ++kc)
            av[kc] = *reinterpret_cast<const short8*>(&hbf[cb][l15][kc * 32 + g4 * 8]);

        floatx4 C[3];
        #pragma unroll
        for (int u = 0; u < 3; ++u) C[u] = (floatx4){br[u], br[u], br[u], br[u]};
        #pragma unroll
        for (int kc = 0; kc < 8; ++kc) {
            #pragma unroll
            for (int u = 0; u < 3; ++u)
                C[u] = __builtin_amdgcn_mfma_f32_16x16x32_bf16(av[kc], Bf[u][kc], C[u], 0, 0, 0);
        }

        // gates: C[u][j] = r{z,r,h}(seq = g4*4+j, col d), biases already in C
        #pragma unroll
        for (int j = 0; j < 4; ++j) {
            float tz = C[0][j] + xq[0][j];                       // log2e * (xz+rz)
            float tr = C[1][j] + xq[1][j];
            float z  = frcp(1.f + __builtin_amdgcn_exp2f(-tz));  // sigmoid
            float r  = frcp(1.f + __builtin_amdgcn_exp2f(-tr));
            float th = fmaf(r, C[2][j], xq[2][j]);               // 2log2e * (xh+r*rh)
            float hh = 1.f - 2.f * frcp(1.f + __builtin_amdgcn_exp2f(th));  // tanh
            h[j] = hh + z * (h[j] - hh);                         // z*h + (1-z)*hh
            const int seq = g4 * 4 + j;
            out[(size_t)(seq * SEQ + s) * HID + d] = h[j];
            hbf[nb][seq][d] = bf16bits(h[j]);
        }
    }
}

extern "C" void kernel_launch(void* const* d_in, const int* in_sizes, int n_in,
                              void* d_out, int out_size, void* d_ws, size_t ws_size,
                              hipStream_t stream) {
    const float* feat = (const float*)d_in[0];
    const float* w1   = (const float*)d_in[1];
    const float* w2   = (const float*)d_in[2];
    const float* bias = (const float*)d_in[3];
    const float* v3   = (const float*)d_in[4];
    const float* gk   = (const float*)d_in[5];
    const float* grk  = (const float*)d_in[6];
    const float* gb   = (const float*)d_in[7];
    float* out = (float*)d_out;

    char* wsb = (char*)d_ws;
    float* left  = (float*)(wsb);
    float* right = (float*)(wsb + (size_t)2 * 1024 * 1024);
    float* cbuf  = (float*)(wsb + (size_t)4 * 1024 * 1024);
    float* xp    = (float*)(wsb + (size_t)6 * 1024 * 1024);

    k1_leftright<<<2048 / 8, 256, 0, stream>>>(feat, w1, w2, left, right);
    k2_attn<<<NSEQ * SEQ, 128, 0, stream>>>(feat, left, right, bias, v3, cbuf);
    k3_xproj<<<2048 / 8, 256, 0, stream>>>(feat, cbuf, gk, gb, xp);
    k4_gru<<<1, 1024, 0, stream>>>(grk, gb, xp, out);
}

// Round 5
// 546.751 us; speedup vs baseline: 1.8490x; 1.8490x over previous
//
#include <hip/hip_runtime.h>
#include <hip/hip_bf16.h>

typedef __attribute__((ext_vector_type(8))) short short8;
typedef __attribute__((ext_vector_type(4))) float floatx4;

#define NSEQ 16
#define SEQ 128
#define DIM 256
#define HID 256
#define K3H 768
#define K2D 512
#define LOG2E 1.442695041f
#define LOG2E2 2.885390082f

__device__ __forceinline__ float frcp(float x) { return __builtin_amdgcn_rcpf(x); }
__device__ __forceinline__ float ftanh(float x) {
    return 1.f - 2.f * frcp(1.f + __expf(2.f * x));
}
__device__ __forceinline__ unsigned short bf16bits(float v) {
    unsigned u = __builtin_bit_cast(unsigned, v);
    unsigned r = (u + 0x7FFFu + ((u >> 16) & 1u)) >> 16;
    return (unsigned short)r;
}

// ---------------- K1: left = x@w1, right = x@w2  (8 rows/block) ----------------
__global__ __launch_bounds__(256) void k1_leftright(
        const float* __restrict__ x, const float* __restrict__ w1,
        const float* __restrict__ w2, float* __restrict__ left,
        float* __restrict__ right) {
    __shared__ __align__(16) float xs[8][DIM];
    const int tid = threadIdx.x;
    const int r0 = blockIdx.x * 8;
    #pragma unroll
    for (int i = 0; i < 8; ++i) xs[i][tid] = x[(r0 + i) * DIM + tid];
    __syncthreads();
    float accL[8], accR[8];
    #pragma unroll
    for (int i = 0; i < 8; ++i) { accL[i] = 0.f; accR[i] = 0.f; }
    #pragma unroll 4
    for (int d = 0; d < DIM; ++d) {
        float wa = w1[d * DIM + tid];
        float wb = w2[d * DIM + tid];
        #pragma unroll
        for (int i = 0; i < 8; ++i) {
            float xv = xs[i][d];
            accL[i] = fmaf(xv, wa, accL[i]);
            accR[i] = fmaf(xv, wb, accR[i]);
        }
    }
    #pragma unroll
    for (int i = 0; i < 8; ++i) {
        left[(r0 + i) * DIM + tid]  = accL[i];
        right[(r0 + i) * DIM + tid] = accR[i];
    }
}

// ---------------- K2: scores (tanh, v3 dot), softmax, c = score@x ----------------
__global__ __launch_bounds__(128) void k2_attn(
        const float* __restrict__ x, const float* __restrict__ left,
        const float* __restrict__ right, const float* __restrict__ bias,
        const float* __restrict__ v3, float* __restrict__ cout) {
    __shared__ __align__(16) float lm[DIM];
    __shared__ __align__(16) float v3s[DIM];
    __shared__ float p[SEQ];
    __shared__ float red[2];
    const int tid = threadIdx.x;      // 0..127 (= n)
    const int lane = tid & 63;
    const int wid = tid >> 6;         // 0..1
    const int bm = blockIdx.x;        // 0..2047
    const int b = bm >> 7;            // sequence index

    const float* lrow = left + bm * DIM;
    #pragma unroll
    for (int q = 0; q < 2; ++q) {
        int d = tid + q * 128;
        lm[d]  = lrow[d] + bias[d];
        v3s[d] = v3[d];
    }
    __syncthreads();

    const float4* rrow = reinterpret_cast<const float4*>(right + (b * SEQ + tid) * DIM);
    const float4* lm4  = reinterpret_cast<const float4*>(lm);
    const float4* vv4  = reinterpret_cast<const float4*>(v3s);
    float s = 0.f;
    for (int d4 = 0; d4 < DIM / 4; ++d4) {
        float4 rv = rrow[d4];
        float4 lv = lm4[d4];
        float4 vv = vv4[d4];
        s = fmaf(ftanh(lv.x + rv.x), vv.x, s);
        s = fmaf(ftanh(lv.y + rv.y), vv.y, s);
        s = fmaf(ftanh(lv.z + rv.z), vv.z, s);
        s = fmaf(ftanh(lv.w + rv.w), vv.w, s);
    }
    float m = s;
    #pragma unroll
    for (int off = 32; off >= 1; off >>= 1) m = fmaxf(m, __shfl_xor(m, off, 64));
    if (lane == 0) red[wid] = m;
    __syncthreads();
    m = fmaxf(red[0], red[1]);
    float e = __expf(s - m);
    float t = e;
    #pragma unroll
    for (int off = 32; off >= 1; off >>= 1) t += __shfl_xor(t, off, 64);
    __syncthreads();
    if (lane == 0) red[wid] = t;
    __syncthreads();
    float denom = red[0] + red[1];
    p[tid] = e * frcp(denom);
    __syncthreads();

    const float* xb = x + b * SEQ * DIM;
    float c0 = 0.f, c1 = 0.f;
    #pragma unroll 4
    for (int n = 0; n < SEQ; ++n) {
        float pn = p[n];
        c0 = fmaf(pn, xb[n * DIM + tid], c0);
        c1 = fmaf(pn, xb[n * DIM + tid + 128], c1);
    }
    cout[bm * DIM + tid]       = c0;
    cout[bm * DIM + tid + 128] = c1;
}

// ---------------- K3: xp = [x, c] @ gru_kernel + b_in  (8 rows/block) ----------------
// z/r outputs prescaled by log2e, h outputs by 2*log2e so k4's sigmoid/tanh
// become bare exp2 with negate modifiers.
__global__ __launch_bounds__(256) void k3_xproj(
        const float* __restrict__ x, const float* __restrict__ c,
        const float* __restrict__ gk, const float* __restrict__ gbias,
        float* __restrict__ xp) {
    __shared__ __align__(16) float xc[8][K2D];
    const int tid = threadIdx.x;
    const int r0 = blockIdx.x * 8;
    #pragma unroll
    for (int i = 0; i < 8; ++i) {
        xc[i][tid]       = x[(r0 + i) * DIM + tid];
        xc[i][tid + 256] = c[(r0 + i) * DIM + tid];
    }
    __syncthreads();
    float acc[8][3];
    #pragma unroll
    for (int i = 0; i < 8; ++i) {
        acc[i][0] = gbias[tid];
        acc[i][1] = gbias[256 + tid];
        acc[i][2] = gbias[512 + tid];
    }
    #pragma unroll 2
    for (int k = 0; k < K2D; ++k) {
        float g0 = gk[k * K3H + tid];
        float g1 = gk[k * K3H + 256 + tid];
        float g2 = gk[k * K3H + 512 + tid];
        #pragma unroll
        for (int i = 0; i < 8; ++i) {
            float xv = xc[i][k];
            acc[i][0] = fmaf(xv, g0, acc[i][0]);
            acc[i][1] = fmaf(xv, g1, acc[i][1]);
            acc[i][2] = fmaf(xv, g2, acc[i][2]);
        }
    }
    #pragma unroll
    for (int i = 0; i < 8; ++i) {
        xp[(r0 + i) * K3H + tid]       = acc[i][0] * LOG2E;
        xp[(r0 + i) * K3H + 256 + tid] = acc[i][1] * LOG2E;
        xp[(r0 + i) * K3H + 512 + tid] = acc[i][2] * LOG2E2;
    }
}

// ---------------- K4: GRU recurrence v5 ----------------
// 16 blocks (1 seq each), 512 threads (8 waves). Wave wv owns cols {32wv..32wv+31}
// of EACH gate: tiles u=g*2+t, col = g*256 + 32wv + 16t + l15. Gates in-register
// from C (lanes 0-15, reg 0). Weights prescaled bf16 in 192 regs (v1-proven).
// ONE raw lgkm-only barrier per step (no vmcnt drain ever). hbf + xq double-
// buffered in LDS. xp prefetched at distance 2: global->reg at s (for s+2),
// reg->LDS at s+1, consumed at s+2 -> a full iteration in flight, no stall.
// A-fragment: exec-masked ds_read into PRE-ZEROED persistent regs (lanes with
// l15!=0 never written -> stay zero; zero VALU cost per step).
__global__ __launch_bounds__(512, 2) void k4_gru(
        const float* __restrict__ rec, const float* __restrict__ gbias,
        const float* __restrict__ xp, float* __restrict__ out) {
    __shared__ __align__(16) float ws[16 * K3H];          // 48KB preload staging
    __shared__ __align__(16) unsigned short hbf[2][HID];  // dbuf h (bf16)
    __shared__ __align__(16) float xq[2][K3H];            // dbuf gate inputs (6KB)
    const int tid  = threadIdx.x;
    const int lane = tid & 63;
    const int wv   = tid >> 6;     // 0..7
    const int seq  = blockIdx.x;   // 0..15
    const int l15  = lane & 15;
    const int g4   = lane >> 4;    // 0..3

    // ---- Preload rec_kernel as prescaled bf16 B-fragments ----
    short8 Bf[6][8];
    #pragma unroll
    for (int part = 0; part < 16; ++part) {
        #pragma unroll
        for (int q = 0; q < 6; ++q) {
            int fi = q * 512 + tid;   // 3072 float4 = 16*768 floats
            reinterpret_cast<float4*>(ws)[fi] =
                reinterpret_cast<const float4*>(rec + part * 16 * K3H)[fi];
        }
        __syncthreads();
        const int kc = part >> 1, half = part & 1;
        #pragma unroll
        for (int u = 0; u < 6; ++u) {
            const float sc = (u >= 4) ? LOG2E2 : LOG2E;
            const int col = (u >> 1) * 256 + wv * 32 + (u & 1) * 16 + l15;
            #pragma unroll
            for (int j = 0; j < 8; ++j) {
                int r = g4 * 8 + j;            // k within 32-chunk
                if ((r >> 4) == half)
                    Bf[u][kc][j] = (short)bf16bits(ws[(r & 15) * K3H + col] * sc);
            }
        }
        __syncthreads();
    }

    const int d0 = wv * 32 + l15;   // t=0 column owned by gate lanes
    const int d1 = d0 + 16;         // t=1 column
    float br[6];
    #pragma unroll
    for (int u = 0; u < 6; ++u) {
        const float sc = (u >= 4) ? LOG2E2 : LOG2E;
        br[u] = gbias[K3H + (u >> 1) * 256 + (u & 1) * 16 + d0] * sc;
    }

    float h0 = 0.f, h1 = 0.f;
    if (tid < HID) hbf[0][tid] = 0;

    const float* xps = xp + (size_t)seq * SEQ * K3H;
    float* outs = out + (size_t)seq * SEQ * HID;

    // prologue: xq[0] = row 0 (direct); prefetch row 1 into regs
    xq[0][tid] = xps[tid];
    if (tid < 256) xq[0][512 + tid] = xps[512 + tid];
    float pA = xps[K3H + tid];
    float pB = (tid < 256) ? xps[K3H + 512 + tid] : 0.f;

    // persistent pre-zeroed A-fragments
    short8 av[8];
    #pragma unroll
    for (int kc = 0; kc < 8; ++kc) av[kc] = (short8){0, 0, 0, 0, 0, 0, 0, 0};

    __syncthreads();

    for (int s = 0; s < SEQ; ++s) {
        const int cb = s & 1, nb = cb ^ 1;

        // (A) issue global loads for row s+2 (consumed as LDS write next iter)
        float gA = 0.f, gB = 0.f;
        if (s + 2 < SEQ) {
            gA = xps[(s + 2) * K3H + tid];
            if (tid < 256) gB = xps[(s + 2) * K3H + 512 + tid];
        }
        // (B) stage row s+1 into LDS (regs issued a full iteration ago)
        if (s + 1 < SEQ) {
            xq[nb][tid] = pA;
            if (tid < 256) xq[nb][512 + tid] = pB;
        }
        // (C) A-fragments: exec-masked reads, only l15==0 lanes written
        if (l15 == 0) {
            #pragma unroll
            for (int kc = 0; kc < 8; ++kc)
                av[kc] = *reinterpret_cast<const short8*>(&hbf[cb][kc * 32 + g4 * 8]);
        }
        // (D) rp = h @ rec (M=1), bias pre-folded into C row 0
        floatx4 C[6];
        #pragma unroll
        for (int u = 0; u < 6; ++u) C[u] = (floatx4){br[u], 0.f, 0.f, 0.f};
        #pragma unroll
        for (int kc = 0; kc < 8; ++kc) {
            #pragma unroll
            for (int u = 0; u < 6; ++u)
                C[u] = __builtin_amdgcn_mfma_f32_16x16x32_bf16(av[kc], Bf[u][kc], C[u], 0, 0, 0);
        }
        // (E) gates: lanes 0-15 own (d0, d1); C row0 = reg0 of lanes 0-15
        if (lane < 16) {
            float tz0 = C[0][0] + xq[cb][d0];
            float tz1 = C[1][0] + xq[cb][d1];
            float tr0 = C[2][0] + xq[cb][256 + d0];
            float tr1 = C[3][0] + xq[cb][256 + d1];
            float z0 = frcp(1.f + __builtin_amdgcn_exp2f(-tz0));
            float z1 = frcp(1.f + __builtin_amdgcn_exp2f(-tz1));
            float r0 = frcp(1.f + __builtin_amdgcn_exp2f(-tr0));
            float r1 = frcp(1.f + __builtin_amdgcn_exp2f(-tr1));
            float th0 = fmaf(r0, C[4][0], xq[cb][512 + d0]);
            float th1 = fmaf(r1, C[5][0], xq[cb][512 + d1]);
            float hh0 = 1.f - 2.f * frcp(1.f + __builtin_amdgcn_exp2f(th0));
            float hh1 = 1.f - 2.f * frcp(1.f + __builtin_amdgcn_exp2f(th1));
            h0 = hh0 + z0 * (h0 - hh0);
            h1 = hh1 + z1 * (h1 - hh1);
            outs[s * HID + d0] = h0;
            outs[s * HID + d1] = h1;
            hbf[nb][d0] = bf16bits(h0);
            hbf[nb][d1] = bf16bits(h1);
        }
        pA = gA; pB = gB;
        // ONE raw barrier per step: LDS drained, globals stay in flight
        asm volatile("s_waitcnt lgkmcnt(0)\n\ts_barrier" ::: "memory");
    }
}

extern "C" void kernel_launch(void* const* d_in, const int* in_sizes, int n_in,
                              void* d_out, int out_size, void* d_ws, size_t ws_size,
                              hipStream_t stream) {
    const float* feat = (const float*)d_in[0];
    const float* w1   = (const float*)d_in[1];
    const float* w2   = (const float*)d_in[2];
    const float* bias = (const float*)d_in[3];
    const float* v3   = (const float*)d_in[4];
    const float* gk   = (const float*)d_in[5];
    const float* grk  = (const float*)d_in[6];
    const float* gb   = (const float*)d_in[7];
    float* out = (float*)d_out;

    char* wsb = (char*)d_ws;
    float* left  = (float*)(wsb);
    float* right = (float*)(wsb + (size_t)2 * 1024 * 1024);
    float* cbuf  = (float*)(wsb + (size_t)4 * 1024 * 1024);
    float* xp    = (float*)(wsb + (size_t)6 * 1024 * 1024);

    k1_leftright<<<2048 / 8, 256, 0, stream>>>(feat, w1, w2, left, right);
    k2_attn<<<NSEQ * SEQ, 128, 0, stream>>>(feat, left, right, bias, v3, cbuf);
    k3_xproj<<<2048 / 8, 256, 0, stream>>>(feat, cbuf, gk, gb, xp);
    k4_gru<<<NSEQ, 512, 0, stream>>>(grk, gb, xp, out);
}

// Round 6
// 371.748 us; speedup vs baseline: 2.7194x; 1.4708x over previous
//
#include <hip/hip_runtime.h>
#include <hip/hip_bf16.h>

typedef __attribute__((ext_vector_type(8))) short short8;
typedef __attribute__((ext_vector_type(4))) float floatx4;

#define NSEQ 16
#define SEQ 128
#define DIM 256
#define HID 256
#define K3H 768
#define K2D 512
#define LOG2E 1.442695041f
#define LOG2E2 2.885390082f
#define WS_STRIDE 772   // 768 + 4: breaks 16-way preload bank conflict to 2-way (free)

__device__ __forceinline__ float frcp(float x) { return __builtin_amdgcn_rcpf(x); }
__device__ __forceinline__ float ftanh(float x) {
    return 1.f - 2.f * frcp(1.f + __expf(2.f * x));
}
__device__ __forceinline__ unsigned short bf16bits(float v) {
    unsigned u = __builtin_bit_cast(unsigned, v);
    unsigned r = (u + 0x7FFFu + ((u >> 16) & 1u)) >> 16;
    return (unsigned short)r;
}
// async global->LDS DMA, 16B/lane: LDS dest = uniform base + lane*16 (HW rule)
__device__ __forceinline__ void load_lds16(const float* gsrc, float* ldsbase) {
    __builtin_amdgcn_global_load_lds(
        (const __attribute__((address_space(1))) void*)gsrc,
        (__attribute__((address_space(3))) void*)ldsbase, 16, 0, 0);
}

// ---------------- K1: left = x@w1, right = x@w2  (8 rows/block, v1-proven) ----------------
__global__ __launch_bounds__(256) void k1_leftright(
        const float* __restrict__ x, const float* __restrict__ w1,
        const float* __restrict__ w2, float* __restrict__ left,
        float* __restrict__ right) {
    __shared__ __align__(16) float xs[8][DIM];
    const int tid = threadIdx.x;
    const int r0 = blockIdx.x * 8;
    #pragma unroll
    for (int i = 0; i < 8; ++i) xs[i][tid] = x[(r0 + i) * DIM + tid];
    __syncthreads();
    float accL[8], accR[8];
    #pragma unroll
    for (int i = 0; i < 8; ++i) { accL[i] = 0.f; accR[i] = 0.f; }
    #pragma unroll 4
    for (int d = 0; d < DIM; ++d) {
        float wa = w1[d * DIM + tid];
        float wb = w2[d * DIM + tid];
        #pragma unroll
        for (int i = 0; i < 8; ++i) {
            float xv = xs[i][d];
            accL[i] = fmaf(xv, wa, accL[i]);
            accR[i] = fmaf(xv, wb, accR[i]);
        }
    }
    #pragma unroll
    for (int i = 0; i < 8; ++i) {
        left[(r0 + i) * DIM + tid]  = accL[i];
        right[(r0 + i) * DIM + tid] = accR[i];
    }
}

// ---------------- K2: scores (tanh, v3 dot), softmax, c = score@x ----------------
__global__ __launch_bounds__(128) void k2_attn(
        const float* __restrict__ x, const float* __restrict__ left,
        const float* __restrict__ right, const float* __restrict__ bias,
        const float* __restrict__ v3, float* __restrict__ cout) {
    __shared__ __align__(16) float lm[DIM];
    __shared__ __align__(16) float v3s[DIM];
    __shared__ float p[SEQ];
    __shared__ float red[2];
    const int tid = threadIdx.x;      // 0..127 (= n)
    const int lane = tid & 63;
    const int wid = tid >> 6;         // 0..1
    const int bm = blockIdx.x;        // 0..2047
    const int b = bm >> 7;            // sequence index

    const float* lrow = left + bm * DIM;
    #pragma unroll
    for (int q = 0; q < 2; ++q) {
        int d = tid + q * 128;
        lm[d]  = lrow[d] + bias[d];
        v3s[d] = v3[d];
    }
    __syncthreads();

    const float4* rrow = reinterpret_cast<const float4*>(right + (b * SEQ + tid) * DIM);
    const float4* lm4  = reinterpret_cast<const float4*>(lm);
    const float4* vv4  = reinterpret_cast<const float4*>(v3s);
    float s = 0.f;
    for (int d4 = 0; d4 < DIM / 4; ++d4) {
        float4 rv = rrow[d4];
        float4 lv = lm4[d4];
        float4 vv = vv4[d4];
        s = fmaf(ftanh(lv.x + rv.x), vv.x, s);
        s = fmaf(ftanh(lv.y + rv.y), vv.y, s);
        s = fmaf(ftanh(lv.z + rv.z), vv.z, s);
        s = fmaf(ftanh(lv.w + rv.w), vv.w, s);
    }
    float m = s;
    #pragma unroll
    for (int off = 32; off >= 1; off >>= 1) m = fmaxf(m, __shfl_xor(m, off, 64));
    if (lane == 0) red[wid] = m;
    __syncthreads();
    m = fmaxf(red[0], red[1]);
    float e = __expf(s - m);
    float t = e;
    #pragma unroll
    for (int off = 32; off >= 1; off >>= 1) t += __shfl_xor(t, off, 64);
    __syncthreads();
    if (lane == 0) red[wid] = t;
    __syncthreads();
    float denom = red[0] + red[1];
    p[tid] = e * frcp(denom);
    __syncthreads();

    const float* xb = x + b * SEQ * DIM;
    float c0 = 0.f, c1 = 0.f;
    #pragma unroll 4
    for (int n = 0; n < SEQ; ++n) {
        float pn = p[n];
        c0 = fmaf(pn, xb[n * DIM + tid], c0);
        c1 = fmaf(pn, xb[n * DIM + tid + 128], c1);
    }
    cout[bm * DIM + tid]       = c0;
    cout[bm * DIM + tid + 128] = c1;
}

// ---------------- K3: xp = [x, c] @ gru_kernel + b_in  (8 rows/block) ----------------
// z/r outputs prescaled by log2e, h by 2*log2e (validated r4/r5).
__global__ __launch_bounds__(256) void k3_xproj(
        const float* __restrict__ x, const float* __restrict__ c,
        const float* __restrict__ gk, const float* __restrict__ gbias,
        float* __restrict__ xp) {
    __shared__ __align__(16) float xc[8][K2D];
    const int tid = threadIdx.x;
    const int r0 = blockIdx.x * 8;
    #pragma unroll
    for (int i = 0; i < 8; ++i) {
        xc[i][tid]       = x[(r0 + i) * DIM + tid];
        xc[i][tid + 256] = c[(r0 + i) * DIM + tid];
    }
    __syncthreads();
    float acc[8][3];
    #pragma unroll
    for (int i = 0; i < 8; ++i) {
        acc[i][0] = gbias[tid];
        acc[i][1] = gbias[256 + tid];
        acc[i][2] = gbias[512 + tid];
    }
    #pragma unroll 2
    for (int k = 0; k < K2D; ++k) {
        float g0 = gk[k * K3H + tid];
        float g1 = gk[k * K3H + 256 + tid];
        float g2 = gk[k * K3H + 512 + tid];
        #pragma unroll
        for (int i = 0; i < 8; ++i) {
            float xv = xc[i][k];
            acc[i][0] = fmaf(xv, g0, acc[i][0]);
            acc[i][1] = fmaf(xv, g1, acc[i][1]);
            acc[i][2] = fmaf(xv, g2, acc[i][2]);
        }
    }
    #pragma unroll
    for (int i = 0; i < 8; ++i) {
        xp[(r0 + i) * K3H + tid]       = acc[i][0] * LOG2E;
        xp[(r0 + i) * K3H + 256 + tid] = acc[i][1] * LOG2E;
        xp[(r0 + i) * K3H + 512 + tid] = acc[i][2] * LOG2E2;
    }
}

// ---------------- K4: GRU recurrence v6 = v1 skeleton + DMA prefetch ----------------
// 16 blocks (1 seq), 512 threads (8 waves). v1's proven shape: wave wv owns cols
// [wv*96, wv*96+96) (6 tiles), rp round-trip through LDS, gates on tid<256, two
// barriers/step. Changes vs v1:
//  (1) xp gate inputs arrive via global_load_lds DMA at distance 2 into a triple-
//      buffered LDS xq — no VGPR round-trip, so no waitcnt on fresh loads ever.
//  (2) barrier1 = s_waitcnt vmcnt(4) lgkmcnt(0); s_barrier  (counted vmcnt: 4 ops
//      issued after the xq batch being consumed: st,ld,st,ld). barrier2 lgkm-only.
//      Loads/stores stay in flight across barriers (m201 pattern).
//  (3) bias folded into MFMA C-init; log2e/2log2e prescale (validated r4/r5).
//  (4) preload staging padded 768->772 floats/row: 16-way -> 2-way (free) conflict.
__global__ __launch_bounds__(512, 2) void k4_gru(
        const float* __restrict__ rec, const float* __restrict__ gbias,
        const float* __restrict__ xp, float* __restrict__ out) {
    __shared__ __align__(16) float ws[16 * WS_STRIDE];    // 49.4KB preload staging
    __shared__ __align__(16) float xq[3][K3H];            // 9KB  triple-buffered gate inputs
    __shared__ __align__(16) float rp[K3H];               // 3KB  recurrent projections
    __shared__ __align__(16) unsigned short hbf[HID];     // 0.5KB h (bf16)
    const int tid  = threadIdx.x;
    const int lane = tid & 63;
    const int wv   = tid >> 6;     // 0..7
    const int seq  = blockIdx.x;   // 0..15
    const int l15  = lane & 15;
    const int g4   = lane >> 4;    // 0..3

    // ---- Preload rec_kernel as prescaled bf16 B-fragments ----
    short8 Bf[6][8];
    #pragma unroll
    for (int part = 0; part < 16; ++part) {
        #pragma unroll
        for (int q = 0; q < 6; ++q) {
            int fi = q * 512 + tid;            // 3072 float4 = 16 rows x 192 float4
            int row = fi / 192, c4 = fi % 192;
            reinterpret_cast<float4*>(ws)[row * (WS_STRIDE / 4) + c4] =
                reinterpret_cast<const float4*>(rec + part * 16 * K3H)[fi];
        }
        __syncthreads();
        const int kc = part >> 1, half = part & 1;
        #pragma unroll
        for (int u = 0; u < 6; ++u) {
            const int colbase = wv * 96 + u * 16;
            const float sc = (colbase >= 512) ? LOG2E2 : LOG2E;
            const int col = colbase + l15;
            #pragma unroll
            for (int j = 0; j < 8; ++j) {
                int r = g4 * 8 + j;            // k within 32-chunk
                if ((r >> 4) == half)
                    Bf[u][kc][j] = (short)bf16bits(ws[(r & 15) * WS_STRIDE + col] * sc);
            }
        }
        __syncthreads();
    }

    // per-lane bias fold (C-init); row 0 is the only row consumed
    floatx4 br4[6];
    #pragma unroll
    for (int u = 0; u < 6; ++u) {
        const int colbase = wv * 96 + u * 16;
        const float sc = (colbase >= 512) ? LOG2E2 : LOG2E;
        const float b = gbias[K3H + colbase + l15] * sc;
        br4[u] = (floatx4){b, b, b, b};
    }

    const float* xps = xp + (size_t)seq * SEQ * K3H;
    float* outs = out + (size_t)seq * SEQ * HID;

    float h = 0.f;                       // tid<256: h for column d=tid
    if (tid < HID) hbf[tid] = 0;

    // prologue: DMA rows 0 and 1 into xq[0], xq[1]; full drain once
    if (wv < 3) {
        load_lds16(xps + wv * 256 + (lane << 2),       &xq[0][wv * 256]);
        load_lds16(xps + K3H + wv * 256 + (lane << 2), &xq[1][wv * 256]);
    }
    asm volatile("s_waitcnt vmcnt(0)" ::: "memory");
    __syncthreads();

    const short8 zero8 = {0, 0, 0, 0, 0, 0, 0, 0};
    int bc = 0, bn2 = 2;                 // xq buffer for step s, and for s+2
    for (int s = 0; s < SEQ; ++s) {
        // (A) DMA prefetch row s+2 (waves 0-2; 256 floats each; no VGPR round-trip)
        if (wv < 3 && s + 2 < SEQ)
            load_lds16(xps + (s + 2) * K3H + wv * 256 + (lane << 2), &xq[bn2][wv * 256]);

        // (B) rp = h @ rec (M=1), bias pre-folded into C
        floatx4 C[6];
        #pragma unroll
        for (int u = 0; u < 6; ++u) C[u] = br4[u];
        #pragma unroll
        for (int kc = 0; kc < 8; ++kc) {
            short8 a = zero8;
            if (l15 == 0)
                a = *reinterpret_cast<const short8*>(&hbf[kc * 32 + g4 * 8]);
            #pragma unroll
            for (int u = 0; u < 6; ++u)
                C[u] = __builtin_amdgcn_mfma_f32_16x16x32_bf16(a, Bf[u][kc], C[u], 0, 0, 0);
        }
        // (C) write rp (row 0 = reg 0 of lanes 0-15)
        if (lane < 16) {
            #pragma unroll
            for (int u = 0; u < 6; ++u)
                rp[wv * 96 + u * 16 + lane] = C[u][0];
        }
        // barrier1: counted vmcnt — xq[bc]'s DMA (2 steps old) retired at <=4
        // outstanding (st,ld,st,ld issued after it); loads for s+1/s+2 stay in flight
        asm volatile("s_waitcnt vmcnt(4) lgkmcnt(0)\n\ts_barrier" ::: "memory");

        // (D) gates: thread d = tid < 256
        if (tid < HID) {
            const float* xc = xq[bc];
            float tz = rp[tid]       + xc[tid];          // log2e*(xz+rz)
            float tr = rp[256 + tid] + xc[256 + tid];
            float z  = frcp(1.f + __builtin_amdgcn_exp2f(-tz));
            float r  = frcp(1.f + __builtin_amdgcn_exp2f(-tr));
            float th = fmaf(r, rp[512 + tid], xc[512 + tid]);   // 2log2e*(xh+r*rh)
            float hh = 1.f - 2.f * frcp(1.f + __builtin_amdgcn_exp2f(th));
            h = hh + z * (h - hh);
            outs[s * HID + tid] = h;
            hbf[tid] = bf16bits(h);
        }
        // barrier2: lgkm-only (stores + DMA loads stay in flight)
        asm volatile("s_waitcnt lgkmcnt(0)\n\ts_barrier" ::: "memory");

        bc  = (bc == 2)  ? 0 : bc + 1;
        bn2 = (bn2 == 2) ? 0 : bn2 + 1;
    }
}

extern "C" void kernel_launch(void* const* d_in, const int* in_sizes, int n_in,
                              void* d_out, int out_size, void* d_ws, size_t ws_size,
                              hipStream_t stream) {
    const float* feat = (const float*)d_in[0];
    const float* w1   = (const float*)d_in[1];
    const float* w2   = (const float*)d_in[2];
    const float* bias = (const float*)d_in[3];
    const float* v3   = (const float*)d_in[4];
    const float* gk   = (const float*)d_in[5];
    const float* grk  = (const float*)d_in[6];
    const float* gb   = (const float*)d_in[7];
    float* out = (float*)d_out;

    char* wsb = (char*)d_ws;
    float* left  = (float*)(wsb);
    float* right = (float*)(wsb + (size_t)2 * 1024 * 1024);
    float* cbuf  = (float*)(wsb + (size_t)4 * 1024 * 1024);
    float* xp    = (float*)(wsb + (size_t)6 * 1024 * 1024);

    k1_leftright<<<2048 / 8, 256, 0, stream>>>(feat, w1, w2, left, right);
    k2_attn<<<NSEQ * SEQ, 128, 0, stream>>>(feat, left, right, bias, v3, cbuf);
    k3_xproj<<<2048 / 8, 256, 0, stream>>>(feat, cbuf, gk, gb, xp);
    k4_gru<<<NSEQ, 512, 0, stream>>>(grk, gb, xp, out);
}